// Round 3
// baseline (962.845 us; speedup 1.0000x reference)
//
#include <hip/hip_runtime.h>

// ---------------------------------------------------------------------------
// MultiHeadAttention (softmax over QUERY axis) — MI355X / gfx950, bf16 MFMA.
//
// B=4, S=2048, D=1024, H=16, Dk=64.
// attn[i,j] = exp(s_ij)/L_j, L_j = sum_i exp(s_ij)   (column softmax)
//
// Harness dtype is ambiguous (fp32 reference, bf16-labeled test). Each GEMM
// block sniffs the weight buffer: fp32 buffers read as u16 pairs expose
// huge/NaN "bf16 exponents" (or all-zero low halves if values are
// bf16-rounded fp32); genuine bf16 N(0,sigma) data never does. The sniff is
// deterministic and uniform across blocks.
//
// Workspace (exactly 64 MiB): Q@0 | K@16MiB | V@32MiB | X@48MiB (bf16).
// Rl (column-softmax reciprocals, 512 KiB fp32) lives at d_out+0 and is fully
// consumed by attn_pv before the final GEMM overwrites d_out.
// ---------------------------------------------------------------------------

#define B_   4
#define S_   2048
#define D_   1024
#define H_   16
#define DK_  64
#define BH_  (B_ * H_)
#define SCALE_  0.125f
#define ECLAMP_ 50.0f   // exp arg clamp: exp(50)=5e21 finite; no inf*0 NaN

typedef __bf16 bf16x8 __attribute__((ext_vector_type(8)));
typedef float  f32x4  __attribute__((ext_vector_type(4)));

#define MFMA16(a, b, c) __builtin_amdgcn_mfma_f32_16x16x32_bf16((a), (b), (c), 0, 0, 0)

__device__ __forceinline__ bf16x8 ld8(const __bf16* p) {
    return *reinterpret_cast<const bf16x8*>(p);
}

// Runtime dtype sniff: 1 => buffer is fp32, 0 => buffer is bf16.
// Scans first 2048 u32 words (4096 u16 halves).
//  - fp32 random data: low u16 = float mantissa low bits ~ uniform =>
//    "bf16 exponent" >= 0x90 (|x|>=2^17) occurs w.p. ~0.44/sample.
//  - fp32 holding bf16-rounded values: low u16 == 0 for ALL samples.
//  - true bf16 N(0,sigma<=1) data: exponent <= ~0x82, never all-zero.
__device__ int sniff_fp32(const void* p) {
    __shared__ int s_big, s_nz;
    if (threadIdx.x == 0) { s_big = 0; s_nz = 0; }
    __syncthreads();
    const unsigned int* w = (const unsigned int*)p;
    int big = 0, nz = 0;
    for (int k = threadIdx.x; k < 2048; k += blockDim.x) {
        unsigned int lo = w[k] & 0xFFFFu;
        unsigned int e = (lo >> 7) & 0xFFu;
        if (e >= 0x90u) big = 1;
        if (lo != 0u)   nz = 1;
    }
    if (big) atomicOr(&s_big, 1);
    if (nz)  atomicOr(&s_nz, 1);
    __syncthreads();
    return (s_big || !s_nz) ? 1 : 0;
}

// ---------------------------------------------------------------------------
// GEMM  C[m][n] = sum_k A[m][k] * W[k][n] + bias[n]
//   A: [8192,1024] row-major; W: [1024,1024] row-major ([in][out]).
//   W-tile transposed into LDS during staging (Bs[n][k] <- W[k][n]).
//   A/W/bias dtype = sniffed world (unless a_is_ws: A is bf16 workspace).
//   mode 0: C -> d_out in world dtype, plain [8192,1024]
//   mode 1: C -> ws bf16 as [B,H,S,Dk]
//   256 thr = 4 waves (2x2), 64x64 tile, BK=32, mfma_f32_16x16x32_bf16.
// ---------------------------------------------------------------------------
__global__ __launch_bounds__(256) void gemm_wn(
    const void* __restrict__ A, const void* __restrict__ W,
    const void* __restrict__ bias, void* __restrict__ C,
    int mode, int a_is_ws)
{
    __shared__ __align__(16) __bf16 As[64][48];
    __shared__ __align__(16) __bf16 Bs[64][48];

    const int f32 = sniff_fp32(W);   // includes two __syncthreads

    const int t = threadIdx.x;
    const int lane = t & 63, w = t >> 6;
    const int wm = w >> 1, wn = w & 1;
    const int m0 = blockIdx.y * 64, n0 = blockIdx.x * 64;
    const int alr = t >> 2, alc = (t & 3) * 8;     // A stage: 64 rows x 32 k
    const int bkr = t >> 3, bnc = (t & 7) * 8;     // W stage: 32 k x 64 n
    const int fr = lane & 15, fq = lane >> 4;

    const int a_f32 = (!a_is_ws) && f32;
    const __bf16* Ab = (const __bf16*)A;
    const float*  Af = (const float*)A;
    const __bf16* Wb = (const __bf16*)W;
    const float*  Wf = (const float*)W;

    f32x4 acc[2][2];
#pragma unroll
    for (int i = 0; i < 2; ++i)
#pragma unroll
        for (int j = 0; j < 2; ++j) acc[i][j] = (f32x4){0.f, 0.f, 0.f, 0.f};

    for (int kk = 0; kk < D_; kk += 32) {
        // ---- stage A tile ----
        if (a_f32) {
            const float* ap = &Af[(size_t)(m0 + alr) * D_ + kk + alc];
            float4 x0 = *reinterpret_cast<const float4*>(ap);
            float4 x1 = *reinterpret_cast<const float4*>(ap + 4);
            bf16x8 v;
            v[0] = (__bf16)x0.x; v[1] = (__bf16)x0.y;
            v[2] = (__bf16)x0.z; v[3] = (__bf16)x0.w;
            v[4] = (__bf16)x1.x; v[5] = (__bf16)x1.y;
            v[6] = (__bf16)x1.z; v[7] = (__bf16)x1.w;
            *reinterpret_cast<bf16x8*>(&As[alr][alc]) = v;
        } else {
            *reinterpret_cast<uint4*>(&As[alr][alc]) =
                *reinterpret_cast<const uint4*>(&Ab[(size_t)(m0 + alr) * D_ + kk + alc]);
        }
        // ---- stage W tile (transposed to [n][k]) ----
        if (f32) {
            const float* wp = &Wf[(size_t)(kk + bkr) * D_ + n0 + bnc];
            float4 x0 = *reinterpret_cast<const float4*>(wp);
            float4 x1 = *reinterpret_cast<const float4*>(wp + 4);
            float wvf[8] = {x0.x, x0.y, x0.z, x0.w, x1.x, x1.y, x1.z, x1.w};
#pragma unroll
            for (int u = 0; u < 8; ++u) Bs[bnc + u][bkr] = (__bf16)wvf[u];
        } else {
            bf16x8 wv = ld8(&Wb[(size_t)(kk + bkr) * D_ + n0 + bnc]);
#pragma unroll
            for (int u = 0; u < 8; ++u) Bs[bnc + u][bkr] = wv[u];
        }
        __syncthreads();

        bf16x8 a0 = ld8(&As[wm * 32 + fr][fq * 8]);
        bf16x8 a1 = ld8(&As[wm * 32 + 16 + fr][fq * 8]);
        bf16x8 b0 = ld8(&Bs[wn * 32 + fr][fq * 8]);
        bf16x8 b1 = ld8(&Bs[wn * 32 + 16 + fr][fq * 8]);

        acc[0][0] = MFMA16(a0, b0, acc[0][0]);
        acc[0][1] = MFMA16(a0, b1, acc[0][1]);
        acc[1][0] = MFMA16(a1, b0, acc[1][0]);
        acc[1][1] = MFMA16(a1, b1, acc[1][1]);
        __syncthreads();
    }

#pragma unroll
    for (int mt = 0; mt < 2; ++mt)
#pragma unroll
        for (int nt = 0; nt < 2; ++nt) {
            int colg = n0 + wn * 32 + nt * 16 + fr;             // n (from W)
            float bv = f32 ? ((const float*)bias)[colg]
                           : (float)((const __bf16*)bias)[colg];
#pragma unroll
            for (int r = 0; r < 4; ++r) {
                int rowg = m0 + wm * 32 + mt * 16 + fq * 4 + r; // m (from A)
                float o = acc[mt][nt][r] + bv;
                if (mode == 0) {
                    size_t idx = (size_t)rowg * D_ + colg;
                    if (f32) ((float*)C)[idx] = o;
                    else     ((__bf16*)C)[idx] = (__bf16)o;
                } else {
                    int b = rowg >> 11, sp = rowg & (S_ - 1);
                    int h = colg >> 6, dk = colg & 63;
                    ((__bf16*)C)[(((size_t)(b * H_ + h)) * S_ + sp) * DK_ + dk] = (__bf16)o;
                }
            }
        }
}

// ---------------------------------------------------------------------------
// Column-softmax reciprocals: Rl[bh][j] = 1 / sum_i exp(clamp(scale*Q_i·K_j))
//   MFMA: A = K rows (m=j), B = Q rows (n=i); D[m=j][n=i].
// ---------------------------------------------------------------------------
__global__ __launch_bounds__(256) void colsum_rcp(
    const __bf16* __restrict__ Q, const __bf16* __restrict__ Kp,
    float* __restrict__ Rl)
{
    const int bh = blockIdx.y;
    const int w = threadIdx.x >> 6, lane = threadIdx.x & 63;
    const int j0 = blockIdx.x * 64 + w * 16;
    const int fr = lane & 15, fq = lane >> 4;

    const __bf16* krow = Kp + ((size_t)bh * S_ + j0 + fr) * DK_ + fq * 8;
    bf16x8 ka0 = ld8(krow);
    bf16x8 ka1 = ld8(krow + 32);

    float accl[4] = {0.f, 0.f, 0.f, 0.f};
    for (int i0 = 0; i0 < S_; i0 += 16) {
        const __bf16* qrow = Q + ((size_t)bh * S_ + i0 + fr) * DK_ + fq * 8;
        f32x4 s = (f32x4){0.f, 0.f, 0.f, 0.f};
        s = MFMA16(ka0, ld8(qrow), s);
        s = MFMA16(ka1, ld8(qrow + 32), s);
#pragma unroll
        for (int r = 0; r < 4; ++r)
            accl[r] += __expf(fminf(s[r] * SCALE_, ECLAMP_));
    }

#pragma unroll
    for (int r = 0; r < 4; ++r) {
        accl[r] += __shfl_xor(accl[r], 1, 64);
        accl[r] += __shfl_xor(accl[r], 2, 64);
        accl[r] += __shfl_xor(accl[r], 4, 64);
        accl[r] += __shfl_xor(accl[r], 8, 64);
    }
    if (fr == 0) {
#pragma unroll
        for (int r = 0; r < 4; ++r)
            Rl[(size_t)bh * S_ + j0 + fq * 4 + r] = 1.0f / accl[r];  // accl > 0
    }
}

// ---------------------------------------------------------------------------
// Pass 2: X[i,:] = sum_j (exp(clamp(scale*Q_i·K_j)) * Rl_j) * V[j,:]
// ---------------------------------------------------------------------------
__global__ __launch_bounds__(256) void attn_pv(
    const __bf16* __restrict__ Q, const __bf16* __restrict__ Kp,
    const __bf16* __restrict__ V, const float* __restrict__ Rl,
    __bf16* __restrict__ X)
{
    __shared__ __align__(16) __bf16 Pl[4][16][48];
    __shared__ __align__(16) __bf16 Vs[64][48];    // Vs[d][j], 64 d x 32 j

    const int t = threadIdx.x;
    const int w = t >> 6, lane = t & 63;
    const int bh = blockIdx.y;
    const int i0 = blockIdx.x * 64 + w * 16;
    const int fr = lane & 15, fq = lane >> 4;
    const int vjl = t >> 3, vdk = (t & 7) * 8;     // V stage: 32 j x 64 d

    const __bf16* qrow = Q + ((size_t)bh * S_ + i0 + fr) * DK_ + fq * 8;
    bf16x8 aq0 = ld8(qrow);
    bf16x8 aq1 = ld8(qrow + 32);

    f32x4 acc[4];
#pragma unroll
    for (int i = 0; i < 4; ++i) acc[i] = (f32x4){0.f, 0.f, 0.f, 0.f};

    for (int j0 = 0; j0 < S_; j0 += 32) {
        __syncthreads();   // previous iteration's Vs/Pl reads complete

        bf16x8 vv = ld8(&V[((size_t)bh * S_ + j0 + vjl) * DK_ + vdk]);
#pragma unroll
        for (int u = 0; u < 8; ++u) Vs[vdk + u][vjl] = vv[u];

#pragma unroll
        for (int jt = 0; jt < 2; ++jt) {
            float rl = Rl[(size_t)bh * S_ + j0 + jt * 16 + fr];
            const __bf16* krow = Kp + ((size_t)bh * S_ + j0 + jt * 16 + fr) * DK_ + fq * 8;
            f32x4 s = (f32x4){0.f, 0.f, 0.f, 0.f};
            s = MFMA16(aq0, ld8(krow), s);
            s = MFMA16(aq1, ld8(krow + 32), s);
#pragma unroll
            for (int r = 0; r < 4; ++r)
                Pl[w][fq * 4 + r][jt * 16 + fr] =
                    (__bf16)(__expf(fminf(s[r] * SCALE_, ECLAMP_)) * rl);
        }
        __syncthreads();

        bf16x8 pa = ld8(&Pl[w][fr][fq * 8]);
#pragma unroll
        for (int dt = 0; dt < 4; ++dt) {
            bf16x8 vb = ld8(&Vs[dt * 16 + fr][fq * 8]);
            acc[dt] = MFMA16(pa, vb, acc[dt]);
        }
    }

    const int b = bh >> 4, h = bh & 15;
#pragma unroll
    for (int dt = 0; dt < 4; ++dt)
#pragma unroll
        for (int r = 0; r < 4; ++r) {
            int ig = i0 + fq * 4 + r;
            X[((size_t)b * S_ + ig) * D_ + h * DK_ + dt * 16 + fr] = (__bf16)acc[dt][r];
        }
}

// ---------------------------------------------------------------------------
// Host launcher
// ---------------------------------------------------------------------------
extern "C" void kernel_launch(void* const* d_in, const int* in_sizes, int n_in,
                              void* d_out, int out_size, void* d_ws, size_t ws_size,
                              hipStream_t stream)
{
    const void* query = d_in[0];
    const void* key   = d_in[1];
    const void* value = d_in[2];
    const void* Wq = d_in[3];  const void* bq = d_in[4];
    const void* Wk = d_in[5];  const void* bk = d_in[6];
    const void* Wv = d_in[7];  const void* bv = d_in[8];
    const void* Wo = d_in[9];  const void* bo = d_in[10];

    char* ws = (char*)d_ws;
    const size_t MiB = 1024 * 1024;
    __bf16* Qb = (__bf16*)(ws);              // [B,H,S,Dk] 16 MiB
    __bf16* Kb = (__bf16*)(ws + 16 * MiB);   // 16 MiB
    __bf16* Vb = (__bf16*)(ws + 32 * MiB);   // 16 MiB
    __bf16* Xb = (__bf16*)(ws + 48 * MiB);   // [B,S,D] 16 MiB
    float*  Rlb = (float*)d_out;             // 512 KiB, consumed before final GEMM

    dim3 gg(D_ / 64, (B_ * S_) / 64);
    gemm_wn<<<gg, 256, 0, stream>>>(query, Wq, bq, Qb, 1, 0);
    gemm_wn<<<gg, 256, 0, stream>>>(key,   Wk, bk, Kb, 1, 0);
    gemm_wn<<<gg, 256, 0, stream>>>(value, Wv, bv, Vb, 1, 0);

    colsum_rcp<<<dim3(S_ / 64, BH_), 256, 0, stream>>>(Qb, Kb, Rlb);

    attn_pv<<<dim3(S_ / 64, BH_), 256, 0, stream>>>(Qb, Kb, Vb, Rlb, Xb);

    gemm_wn<<<gg, 256, 0, stream>>>(Xb, Wo, bo, d_out, 0, 1);
}

// Round 5
// 728.829 us; speedup vs baseline: 1.3211x; 1.3211x over previous
//
#include <hip/hip_runtime.h>

// ---------------------------------------------------------------------------
// MultiHeadAttention (softmax over QUERY axis) — MI355X / gfx950, bf16 MFMA.
// B=4, S=2048, D=1024, H=16, Dk=64. Inputs/outputs fp32 (verified round 3).
// attn[i,j] = exp(s_ij)/L_j, L_j = sum_i exp(s_ij)   (column softmax)
// ws (64 MiB): Qb@0 | Kb@16MiB | Vb@32MiB | Xb@48MiB  (bf16 [B,H,S,Dk] / [B,S,D])
// Rl (1/L, 512 KiB fp32) parked in d_out, consumed before final GEMM.
//
// ROUND-5 FIX: fp32 A-staging phase count p<2 (was p<4 -> OOB reads past the
// input buffer => aperture fault/abort, + LDS overflow into Bs). __align__(16)
// restored on all LDS arrays (b128 ops need 16B alignment).
// ---------------------------------------------------------------------------

#define B_   4
#define S_   2048
#define D_   1024
#define H_   16
#define DK_  64
#define BH_  64
#define SCALE_  0.125f
#define EC_     50.0f   // exp clamp: keeps sums finite, no inf*0 NaN

typedef __bf16 bf16x2 __attribute__((ext_vector_type(2)));
typedef __bf16 bf16x4 __attribute__((ext_vector_type(4)));
typedef __bf16 bf16x8 __attribute__((ext_vector_type(8)));
typedef float  f32x4  __attribute__((ext_vector_type(4)));
typedef unsigned int u32;

#define MFMA16(a,b,c) __builtin_amdgcn_mfma_f32_16x16x32_bf16((a),(b),(c),0,0,0)

__device__ __forceinline__ bf16x8 ld8(const __bf16* p){ return *(const bf16x8*)p; }

// async global->LDS, 16B per lane; LDS dest = wave-uniform base + lane*16
__device__ __forceinline__ void gll16(const __bf16* g, __bf16* l) {
    __builtin_amdgcn_global_load_lds(
        (const __attribute__((address_space(1))) u32*)g,
        (__attribute__((address_space(3))) u32*)l, 16, 0, 0);
}

// ---------------------------------------------------------------------------
// GEMM  C[m][n] = sum_k A[m][k]*W[k][n] + bias[n]
//   128x128 tile, BK=32, 4 waves (2x2, 64x64 each), 16 MFMA/iter.
//   ABF16=1: A bf16, staged via global_load_lds (512 chunks of 16B, 2 phases).
//   ABF16=0: A fp32, vector-load + cvt + b128 LDS write (512 items, 2 phases).
//   W fp32 [k][n] -> Bs[n][k] bf16, packed k-pair b32 writes, chunk-XOR swizzle.
//   MODE 0: C fp32 [8192][1024]; MODE 1: C bf16 scatter [B,H,S,Dk].
// ---------------------------------------------------------------------------
template<int ABF16, int MODE>
__global__ __launch_bounds__(256) void gemm128(
    const void* __restrict__ Ap, const float* __restrict__ W,
    const float* __restrict__ bias, void* __restrict__ C)
{
    __shared__ __align__(16) __bf16 As[128*32];   // row-major, row stride 32 elem
    __shared__ __align__(16) __bf16 Bs[128*32];   // [n][k], swizzled 16B chunks

    const int t = threadIdx.x, lane = t & 63, w = t >> 6;
    const int wm = w >> 1, wn = w & 1;
    const int fr = lane & 15, fq = lane >> 4;
    const int m0 = blockIdx.y * 128, n0 = blockIdx.x * 128;

    f32x4 acc[4][4];
#pragma unroll
    for (int i = 0; i < 4; ++i)
#pragma unroll
        for (int j = 0; j < 4; ++j) acc[i][j] = (f32x4){0.f,0.f,0.f,0.f};

    for (int kk = 0; kk < D_; kk += 32) {
        __syncthreads();   // previous iteration's LDS reads complete
        if (ABF16) {
            const __bf16* Ab = (const __bf16*)Ap;
#pragma unroll
            for (int p = 0; p < 2; ++p) {
                int c = p*256 + t;
                gll16(&Ab[(size_t)(m0 + (c>>2))*D_ + kk + (c&3)*8],
                      &As[(size_t)(p*256 + (t & ~63))*8]);
            }
        } else {
            const float* Af = (const float*)Ap;
#pragma unroll
            for (int p = 0; p < 2; ++p) {          // FIX: 2 phases (512 items)
                int c = p*256 + t;
                int row = c >> 2, kc = (c & 3) * 8;
                const float* ap = &Af[(size_t)(m0 + row)*D_ + kk + kc];
                f32x4 x0 = *(const f32x4*)ap;
                f32x4 x1 = *(const f32x4*)(ap + 4);
                bf16x8 v = { (__bf16)x0[0], (__bf16)x0[1], (__bf16)x0[2], (__bf16)x0[3],
                             (__bf16)x1[0], (__bf16)x1[1], (__bf16)x1[2], (__bf16)x1[3] };
                *(bf16x8*)&As[row*32 + kc] = v;
            }
        }
        // W tile: 32k x 128n fp32 -> Bs[n][k] bf16 (pack k-pairs into b32)
#pragma unroll
        for (int p = 0; p < 2; ++p) {
            int idx = p*256 + t;
            int nq = idx >> 4, kp = idx & 15;              // n-quad, k-pair
            const float* wp = &W[(size_t)(kk + 2*kp)*D_ + n0 + nq*4];
            f32x4 w0 = *(const f32x4*)wp;
            f32x4 w1 = *(const f32x4*)(wp + D_);
#pragma unroll
            for (int u = 0; u < 4; ++u) {
                int n = nq*4 + u;
                bf16x2 v = { (__bf16)w0[u], (__bf16)w1[u] };
                *(bf16x2*)&Bs[n*32 + 8*((kp>>2) ^ (n&3)) + 2*(kp&3)] = v;
            }
        }
        __syncthreads();

        bf16x8 af[4], bfr[4];
#pragma unroll
        for (int mt = 0; mt < 4; ++mt)
            af[mt] = ld8(&As[(wm*64 + mt*16 + fr)*32 + fq*8]);
#pragma unroll
        for (int nt = 0; nt < 4; ++nt) {
            int n = wn*64 + nt*16 + fr;
            bfr[nt] = ld8(&Bs[n*32 + 8*(fq ^ (n & 3))]);
        }
#pragma unroll
        for (int mt = 0; mt < 4; ++mt)
#pragma unroll
            for (int nt = 0; nt < 4; ++nt)
                acc[mt][nt] = MFMA16(af[mt], bfr[nt], acc[mt][nt]);
    }

#pragma unroll
    for (int mt = 0; mt < 4; ++mt)
#pragma unroll
        for (int nt = 0; nt < 4; ++nt) {
            int colg = n0 + wn*64 + nt*16 + fr;
            float bv = bias[colg];
#pragma unroll
            for (int r = 0; r < 4; ++r) {
                int rowg = m0 + wm*64 + mt*16 + fq*4 + r;
                float o = acc[mt][nt][r] + bv;
                if (MODE == 0) {
                    ((float*)C)[(size_t)rowg*D_ + colg] = o;
                } else {
                    int b = rowg >> 11, sp = rowg & (S_-1);
                    int h = colg >> 6, dk = colg & 63;
                    ((__bf16*)C)[(((size_t)(b*H_ + h))*S_ + sp)*DK_ + dk] = (__bf16)o;
                }
            }
        }
}

// ---------------------------------------------------------------------------
// Column-softmax reciprocals: Rl[bh][j] = 1/sum_i exp(clamp(scale*Q_i·K_j)).
//   Block = 256 j (4 waves x 64 j); K-frags loop-invariant in regs.
//   Q tile (32 i x 64 dk) staged per step via global_load_lds, i&7 XOR swizzle
//   (row stride 128 B would otherwise hit 16-way conflicts on read).
// ---------------------------------------------------------------------------
__global__ __launch_bounds__(256) void colsum_rcp(
    const __bf16* __restrict__ Q, const __bf16* __restrict__ K,
    float* __restrict__ Rl)
{
    __shared__ __align__(16) __bf16 Qs[32*64];
    const int t = threadIdx.x, lane = t & 63, w = t >> 6;
    const int fr = lane & 15, fq = lane >> 4;
    const int bh = blockIdx.y;
    const int jw = blockIdx.x*256 + w*64;
    const __bf16* Qb = Q + (size_t)bh*S_*DK_;
    const __bf16* Kb = K + (size_t)bh*S_*DK_;

    bf16x8 kh[4][2];
#pragma unroll
    for (int jt = 0; jt < 4; ++jt) {
        const __bf16* kr = &Kb[(size_t)(jw + jt*16 + fr)*DK_];
        kh[jt][0] = ld8(kr + fq*8);
        kh[jt][1] = ld8(kr + 32 + fq*8);
    }

    float accl[4][4] = {};
    for (int i0 = 0; i0 < S_; i0 += 32) {
        __syncthreads();
        {   // chunk t -> row i=t>>3, phys chunk t&7 holds logical kq=(t&7)^(i&7)
            int i = t >> 3, kq = (t & 7) ^ (i & 7);
            gll16(&Qb[(size_t)(i0 + i)*DK_ + kq*8], &Qs[(size_t)(t & ~63)*8]);
        }
        __syncthreads();
#pragma unroll
        for (int it = 0; it < 2; ++it) {
            int i = it*16 + fr;
            bf16x8 q0 = ld8(&Qs[i*64 + 8*(fq ^ (i & 7))]);
            bf16x8 q1 = ld8(&Qs[i*64 + 8*((4 + fq) ^ (i & 7))]);
#pragma unroll
            for (int jt = 0; jt < 4; ++jt) {
                f32x4 s = MFMA16(kh[jt][0], q0, ((f32x4){0.f,0.f,0.f,0.f}));
                s = MFMA16(kh[jt][1], q1, s);
#pragma unroll
                for (int r = 0; r < 4; ++r)
                    accl[jt][r] += __expf(fminf(s[r]*SCALE_, EC_));
            }
        }
    }
#pragma unroll
    for (int jt = 0; jt < 4; ++jt)
#pragma unroll
        for (int r = 0; r < 4; ++r) {
            accl[jt][r] += __shfl_xor(accl[jt][r], 1, 64);
            accl[jt][r] += __shfl_xor(accl[jt][r], 2, 64);
            accl[jt][r] += __shfl_xor(accl[jt][r], 4, 64);
            accl[jt][r] += __shfl_xor(accl[jt][r], 8, 64);
        }
    if (fr == 0) {
#pragma unroll
        for (int jt = 0; jt < 4; ++jt)
#pragma unroll
            for (int r = 0; r < 4; ++r)
                Rl[(size_t)bh*S_ + jw + jt*16 + fq*4 + r] = 1.0f / accl[jt][r];
    }
}

// ---------------------------------------------------------------------------
// Pass 2: X[i,:] = sum_j (exp(clamp(scale*Q_i·K_j)) * Rl_j) * V[j,:]
//   Scores computed TRANSPOSED (A=K, B=Q -> D[j][i]): lane holds 4 consecutive
//   j at fixed i -> packed b64 P-writes in A-operand layout (no scalar LDS).
//   V staged [d][j] with chunk-XOR swizzle (b32 packed writes, b128 reads).
// ---------------------------------------------------------------------------
__global__ __launch_bounds__(256) void attn_pv(
    const __bf16* __restrict__ Q, const __bf16* __restrict__ K,
    const __bf16* __restrict__ V, const float* __restrict__ Rl,
    __bf16* __restrict__ X)
{
    __shared__ __align__(16) __bf16 Pl[4*16*32];  // per-wave: 16 i x 32 j
    __shared__ __align__(16) __bf16 Vs[64*32];    // 64 d x 32 j, swizzled

    const int t = threadIdx.x, lane = t & 63, w = t >> 6;
    const int fr = lane & 15, fq = lane >> 4;
    const int bh = blockIdx.y;
    const int i0 = blockIdx.x*64 + w*16;
    const __bf16* Qb = Q + (size_t)bh*S_*DK_;
    const __bf16* Kb = K + (size_t)bh*S_*DK_;
    const __bf16* Vb = V + (size_t)bh*S_*DK_;
    const float*  Rb = Rl + (size_t)bh*S_;

    bf16x8 aq0 = ld8(&Qb[(size_t)(i0 + fr)*DK_ + fq*8]);
    bf16x8 aq1 = ld8(&Qb[(size_t)(i0 + fr)*DK_ + 32 + fq*8]);

    const int dq  = lane & 15;        // d-quad (d = dq*4+u)
    const int j0p = w*4 + (lane>>4);  // j-pair index 0..15 (j = 2*j0p{,+1})

    f32x4 acc[4];
#pragma unroll
    for (int i = 0; i < 4; ++i) acc[i] = (f32x4){0.f,0.f,0.f,0.f};

    for (int jg = 0; jg < S_; jg += 32) {
        __syncthreads();   // previous step's Vs/Pl reads complete
        // ---- stage Vs[d][j] = V[j][d], packed j-pairs, swizzled chunks ----
        bf16x4 r0 = *(const bf16x4*)&Vb[(size_t)(jg + 2*j0p)*DK_ + dq*4];
        bf16x4 r1 = *(const bf16x4*)&Vb[(size_t)(jg + 2*j0p + 1)*DK_ + dq*4];
#pragma unroll
        for (int u = 0; u < 4; ++u) {
            int d = dq*4 + u;
            bf16x2 v = { r0[u], r1[u] };
            *(bf16x2*)&Vs[d*32 + 8*((j0p>>2) ^ u ^ (dq & 3)) + 2*(j0p & 3)] = v;
        }
        // ---- scores (transposed) -> P in A-layout, b64 packed writes ----
#pragma unroll
        for (int jt = 0; jt < 2; ++jt) {
            f32x4 rl4 = *(const f32x4*)&Rb[jg + jt*16 + fq*4];
            const __bf16* kr = &Kb[(size_t)(jg + jt*16 + fr)*DK_];
            f32x4 s = MFMA16(ld8(kr + fq*8), aq0, ((f32x4){0.f,0.f,0.f,0.f}));
            s = MFMA16(ld8(kr + 32 + fq*8), aq1, s);
            bf16x4 pv;
#pragma unroll
            for (int r = 0; r < 4; ++r)
                pv[r] = (__bf16)(__expf(fminf(s[r]*SCALE_, EC_)) * rl4[r]);
            *(bf16x4*)&Pl[w*512 + fr*32 + jt*16 + fq*4] = pv;
        }
        __syncthreads();   // Vs visible to all waves
        // ---- PV: A = P[i][j], B = Vs[d][j] (swizzled read) ----
        bf16x8 pa = ld8(&Pl[w*512 + fr*32 + fq*8]);
#pragma unroll
        for (int dt = 0; dt < 4; ++dt) {
            int d = dt*16 + fr;
            bf16x8 vb = ld8(&Vs[d*32 + 8*(fq ^ (fr & 3) ^ ((fr >> 2) & 3))]);
            acc[dt] = MFMA16(pa, vb, acc[dt]);
        }
    }

    const int b = bh >> 4, h = bh & 15;
#pragma unroll
    for (int dt = 0; dt < 4; ++dt)
#pragma unroll
        for (int r = 0; r < 4; ++r)
            X[((size_t)b*S_ + i0 + fq*4 + r)*D_ + h*DK_ + dt*16 + fr] =
                (__bf16)acc[dt][r];
}

// ---------------------------------------------------------------------------
// Host launcher
// ---------------------------------------------------------------------------
extern "C" void kernel_launch(void* const* d_in, const int* in_sizes, int n_in,
                              void* d_out, int out_size, void* d_ws, size_t ws_size,
                              hipStream_t stream)
{
    const float* query = (const float*)d_in[0];
    const float* key   = (const float*)d_in[1];
    const float* value = (const float*)d_in[2];
    const float* Wq = (const float*)d_in[3];  const float* bq = (const float*)d_in[4];
    const float* Wk = (const float*)d_in[5];  const float* bk = (const float*)d_in[6];
    const float* Wv = (const float*)d_in[7];  const float* bv = (const float*)d_in[8];
    const float* Wo = (const float*)d_in[9];  const float* bo = (const float*)d_in[10];

    char* ws = (char*)d_ws;
    const size_t MiB = 1024 * 1024;
    __bf16* Qb = (__bf16*)(ws);              // [B,H,S,Dk] 16 MiB
    __bf16* Kb = (__bf16*)(ws + 16 * MiB);
    __bf16* Vb = (__bf16*)(ws + 32 * MiB);
    __bf16* Xb = (__bf16*)(ws + 48 * MiB);   // [B,S,D]
    float*  Rlb = (float*)d_out;             // 512 KiB, consumed before final GEMM

    dim3 gg(D_/128, (B_*S_)/128);            // (8, 64)
    gemm128<0,1><<<gg, 256, 0, stream>>>(query, Wq, bq, Qb);
    gemm128<0,1><<<gg, 256, 0, stream>>>(key,   Wk, bk, Kb);
    gemm128<0,1><<<gg, 256, 0, stream>>>(value, Wv, bv, Vb);

    colsum_rcp<<<dim3(S_/256, BH_), 256, 0, stream>>>(Qb, Kb, Rlb);

    attn_pv<<<dim3(S_/64, BH_), 256, 0, stream>>>(Qb, Kb, Vb, Rlb, Xb);

    gemm128<1,0><<<gg, 256, 0, stream>>>(Xb, Wo, bo, d_out);
}